// Round 1
// baseline (967.997 us; speedup 1.0000x reference)
//
#include <hip/hip_runtime.h>
#include <math.h>

// 2-layer ReLU RNN, B=256, T=1000 (input 800 + zero pad), H=128, F=5.
// One persistent workgroup per batch element; 768 threads = 3 matrix-engine
// groups of 256 (w_hh0 / w_ih1 / w_hh1). Each thread owns a 64-float
// half-row in VGPRs; lane pairs (2i,2i+1) hold the two halves of row i and
// combine via shfl_xor(1). Layers pipelined with 2-step skew through
// double-buffered LDS; ONE __syncthreads per step.
//
// Schedule at step s (read buf p=s&1, write buf q=p^1):
//   grp0: h0[s]   = relu(x[s]Wih0' + h0[s-1]Whh0' + b0)   (s <= 999)
//   grp1: A[s-1]  = Wih1' . h0[s-1]                        (s <= 1000)
//   grp2: h1[s-2] = relu(A[s-2] + Whh1'.h1[s-3] + b1)      (s >= 2)
//   grp1 also: every 8th step, batched sigmoid(w_out.h1) dots from LDS ring.

#define TT    1000
#define TIN   800
#define HD    128
#define NF    5
#define BATCH 256

__global__ __launch_bounds__(768) void rnn_persist(
    const float* __restrict__ x,        // [256,800,5]
    const float* __restrict__ h_state,  // [2,256,128]
    const float* __restrict__ w_ih0,    // [128,5]
    const float* __restrict__ w_hh0,    // [128,128]
    const float* __restrict__ b_ih0,    // [128]
    const float* __restrict__ b_hh0,    // [128]
    const float* __restrict__ w_ih1,    // [128,128]
    const float* __restrict__ w_hh1,    // [128,128]
    const float* __restrict__ b_ih1,    // [128]
    const float* __restrict__ b_hh1,    // [128]
    const float* __restrict__ w_out,    // [1,128]
    const float* __restrict__ b_out,    // [1]
    float* __restrict__ out)            // [204800 y] ++ [65536 final states]
{
    __shared__ float x_lds[TIN * NF];   // 16000 B, this block's x sequence
    __shared__ float h0_lds[2][HD];
    __shared__ float h1_lds[2][HD];
    __shared__ float A_lds[2][HD];
    __shared__ float ring[16][HD];      // h1 history ring for batched y-dots
    __shared__ float wout_lds[HD];

    const int tid  = threadIdx.x;
    const int bb   = blockIdx.x;        // batch element
    const int grp  = tid >> 8;          // 0,1,2 : matrix engine
    const int lt   = tid & 255;
    const int row  = lt >> 1;           // neuron 0..127
    const int half = lt & 1;            // column half 0..1

    // ---- stage x[bb] into LDS (coalesced) ----
    for (int i = tid; i < TIN * NF; i += 768)
        x_lds[i] = x[bb * (TIN * NF) + i];
    if (tid < HD) {
        h0_lds[0][tid] = h_state[bb * HD + tid];
        h1_lds[0][tid] = h_state[BATCH * HD + bb * HD + tid];
    } else if (tid < 2 * HD) {
        wout_lds[tid - HD] = w_out[tid - HD];
    }

    // ---- weights into registers: 64 floats = my half-row ----
    const float* Wsrc = (grp == 0) ? w_hh0 : ((grp == 1) ? w_ih1 : w_hh1);
    float w[64];
    {
        const float4* s4 = (const float4*)(Wsrc + row * HD + half * 64);
        #pragma unroll
        for (int k = 0; k < 16; ++k)
            ((float4*)w)[k] = s4[k];
    }
    float wih0r[NF];
    float bias = 0.f;
    if (grp == 0) {
        #pragma unroll
        for (int f = 0; f < NF; ++f) wih0r[f] = w_ih0[row * NF + f];
        bias = b_ih0[row] + b_hh0[row];
    } else if (grp == 2) {
        bias = b_ih1[row] + b_hh1[row];
    }
    const float bout = b_out[0];

    __syncthreads();

    // 64-deep dot of my half-row against h-half in LDS; 4 acc chains.
    auto dot64 = [&](const float* hbase) -> float {
        const float4* h4 = (const float4*)hbase;
        float a0 = 0.f, a1 = 0.f, a2 = 0.f, a3 = 0.f;
        #pragma unroll
        for (int k = 0; k < 16; ++k) {
            float4 hv = h4[k];
            a0 = fmaf(w[4 * k + 0], hv.x, a0);
            a1 = fmaf(w[4 * k + 1], hv.y, a1);
            a2 = fmaf(w[4 * k + 2], hv.z, a2);
            a3 = fmaf(w[4 * k + 3], hv.w, a3);
        }
        return (a0 + a1) + (a2 + a3);
    };

    for (int s = 0; s < TT + 2; ++s) {
        const int p = s & 1;
        const int q = p ^ 1;

        if (grp == 0) {
            // h0[s] from h0[s-1], x[s]
            if (s < TT) {
                float acc = dot64(&h0_lds[p][half * 64]);
                acc += __shfl_xor(acc, 1, 64);
                if (half == 0) {
                    float v = acc + bias;
                    if (s < TIN) {
                        #pragma unroll
                        for (int f = 0; f < NF; ++f)
                            v = fmaf(wih0r[f], x_lds[s * NF + f], v);
                    }
                    h0_lds[q][row] = fmaxf(v, 0.f);
                }
            }
        } else if (grp == 1) {
            // A[s-1] = Wih1' . h0[s-1]
            if (s <= TT) {
                float acc = dot64(&h0_lds[p][half * 64]);
                acc += __shfl_xor(acc, 1, 64);
                if (half == 0) A_lds[q][row] = acc;
            }
            // batched output dots: 8 sigmoids per visit, every 8th step
            if (s >= 10 && s <= 802 && ((s - 2) & 7) == 0) {
                const int u = (s - 10) + (lt >> 5);  // 8 time-slots x 32 lanes
                const int l = lt & 31;
                const float* hr = ring[u & 15];
                float v = hr[l      ] * wout_lds[l      ]
                        + hr[l + 32] * wout_lds[l + 32]
                        + hr[l + 64] * wout_lds[l + 64]
                        + hr[l + 96] * wout_lds[l + 96];
                v += __shfl_xor(v, 16, 64);
                v += __shfl_xor(v,  8, 64);
                v += __shfl_xor(v,  4, 64);
                v += __shfl_xor(v,  2, 64);
                v += __shfl_xor(v,  1, 64);
                if (l == 0) {
                    float z = v + bout;
                    out[bb * TIN + u] = 1.f / (1.f + expf(-z));
                }
            }
        } else {
            // h1[s-2] from A[s-2], h1[s-3]
            if (s >= 2) {
                const int u = s - 2;
                float acc = dot64(&h1_lds[p][half * 64]);
                acc += __shfl_xor(acc, 1, 64);
                if (half == 0) {
                    float v = acc + bias + A_lds[p][row];
                    v = fmaxf(v, 0.f);
                    h1_lds[q][row] = v;
                    if (u < TIN) ring[u & 15][row] = v;   // feed y-dots
                }
            }
        }
        __syncthreads();
    }

    // After loop: h0_lds[0] = h0[999], h1_lds[0] = h1[999]  (see skew math)
    if (tid < HD) {
        out[TIN * BATCH + bb * HD + tid] = h0_lds[0][tid];
    } else if (tid < 2 * HD) {
        out[TIN * BATCH + BATCH * HD + bb * HD + (tid - HD)] = h1_lds[0][tid - HD];
    }
}

extern "C" void kernel_launch(void* const* d_in, const int* in_sizes, int n_in,
                              void* d_out, int out_size, void* d_ws, size_t ws_size,
                              hipStream_t stream) {
    (void)in_sizes; (void)n_in; (void)d_ws; (void)ws_size; (void)out_size;
    rnn_persist<<<dim3(BATCH), dim3(768), 0, stream>>>(
        (const float*)d_in[0],  (const float*)d_in[1],
        (const float*)d_in[2],  (const float*)d_in[3],
        (const float*)d_in[4],  (const float*)d_in[5],
        (const float*)d_in[6],  (const float*)d_in[7],
        (const float*)d_in[8],  (const float*)d_in[9],
        (const float*)d_in[10], (const float*)d_in[11],
        (float*)d_out);
}

// Round 2
// 550.916 us; speedup vs baseline: 1.7571x; 1.7571x over previous
//
#include <hip/hip_runtime.h>
#include <math.h>

// 2-layer ReLU RNN, B=256, T=1000 (input 800 + zero pad), H=128, F=5.
// One persistent workgroup per batch element; 768 threads = 3 matrix groups
// (w_hh0 / w_ih1 / w_hh1). R2 redesign: each thread owns an 8x8 tile
// (rows rg*8+(j^g), cols c*8..c*8+7) so it reads only 32 B of h from LDS
// per step (R1 was LDS-datapath-bound: 196 KB/CU-step = 2300 DS cyc/step).
// Cross-lane reduction over the 16 lanes sharing a row is ALL-DPP (VALU):
// levels xor1 (quad_perm 0xB1), xor2 (quad_perm 0x4E), xor15 (row_mirror
// 0x140), xor8 (row_ror:8 0x128), with XOR-linear row assignment
// g(c) = 4c0 ^ 2c1 ^ 7c2 making kept-acc indices compile-time.
// __launch_bounds__(768,3): R1's default budget (56 VGPR) spilled w[64].

#define TT    1000
#define TIN   800
#define HD    128
#define NF    5
#define BATCH 256

template<int CTRL>
__device__ __forceinline__ float dpp_mov(float v) {
    union { float f; int i; } u, r;
    u.f = v;
    r.i = __builtin_amdgcn_update_dpp(0, u.i, CTRL, 0xF, 0xF, true);
    return r.f;
}

__global__ __launch_bounds__(768, 3) void rnn_persist(
    const float* __restrict__ x,        // [256,800,5]
    const float* __restrict__ h_state,  // [2,256,128]
    const float* __restrict__ w_ih0,    // [128,5]
    const float* __restrict__ w_hh0,    // [128,128]
    const float* __restrict__ b_ih0,    // [128]
    const float* __restrict__ b_hh0,    // [128]
    const float* __restrict__ w_ih1,    // [128,128]
    const float* __restrict__ w_hh1,    // [128,128]
    const float* __restrict__ b_ih1,    // [128]
    const float* __restrict__ b_hh1,    // [128]
    const float* __restrict__ w_out,    // [1,128]
    const float* __restrict__ b_out,    // [1]
    float* __restrict__ out)            // [204800 y] ++ [65536 final states]
{
    __shared__ float x_lds[TIN * 8];    // stride 8 pad: b128+b32 reads
    __shared__ float h0_lds[2][HD];
    __shared__ float h1_lds[2][HD];
    __shared__ float A_lds[2][HD];
    __shared__ float ring[16][HD];      // h1 history for batched y-dots
    __shared__ float wout_lds[HD];

    const int tid = threadIdx.x;
    const int bb  = blockIdx.x;         // batch element
    const int grp = tid >> 8;           // 0,1,2 : matrix engine
    const int lt  = tid & 255;
    const int c   = lt & 15;            // col chunk / reduction lane
    const int rg  = lt >> 4;            // row group (8 rows)
    const int g   = (4 * (c & 1)) ^ (2 * ((c >> 1) & 1)) ^ (7 * ((c >> 2) & 1));
    const int row = rg * 8 + g;         // row this thread finalizes
    const bool writer = (c & 8) == 0;

    // ---- stage x[bb] into LDS, padded to stride 8 ----
    for (int i = tid; i < TIN * NF; i += 768) {
        int t = i / 5, f = i - 5 * t;
        x_lds[t * 8 + f] = x[bb * (TIN * NF) + i];
    }
    if (tid < HD) {
        h0_lds[0][tid] = h_state[bb * HD + tid];
        h1_lds[0][tid] = h_state[BATCH * HD + bb * HD + tid];
    } else if (tid < 2 * HD) {
        wout_lds[tid - HD] = w_out[tid - HD];
    }

    // ---- weights: acc j <-> row rg*8 + (j^g); cols c*8..c*8+7 ----
    const float* Wsrc = (grp == 0) ? w_hh0 : ((grp == 1) ? w_ih1 : w_hh1);
    float4 wv[16];
    #pragma unroll
    for (int j = 0; j < 8; ++j) {
        const float* rp = Wsrc + (rg * 8 + (j ^ g)) * HD + c * 8;
        wv[2 * j]     = ((const float4*)rp)[0];
        wv[2 * j + 1] = ((const float4*)rp)[1];
    }
    float wih0r[NF];
    float bias = 0.f;
    if (grp == 0) {
        #pragma unroll
        for (int f = 0; f < NF; ++f) wih0r[f] = w_ih0[row * NF + f];
        bias = b_ih0[row] + b_hh0[row];
    } else if (grp == 2) {
        bias = b_ih1[row] + b_hh1[row];
    }
    const float bout = b_out[0];

    __syncthreads();

    // 8x8 tile matvec + all-DPP 16-lane reduction. Result valid in all lanes
    // (lane c and c^8 both hold row rg*8+g's full dot).
    auto matvec = [&](const float* hbuf) -> float {
        const float4* h4 = (const float4*)(hbuf + c * 8);
        float4 ha = h4[0], hb = h4[1];
        float a[8];
        #pragma unroll
        for (int j = 0; j < 8; ++j) {
            float4 w0 = wv[2 * j], w1 = wv[2 * j + 1];
            float aj = w0.x * ha.x;
            aj = fmaf(w0.y, ha.y, aj);
            aj = fmaf(w0.z, ha.z, aj);
            aj = fmaf(w0.w, ha.w, aj);
            aj = fmaf(w1.x, hb.x, aj);
            aj = fmaf(w1.y, hb.y, aj);
            aj = fmaf(w1.z, hb.z, aj);
            aj = fmaf(w1.w, hb.w, aj);
            a[j] = aj;
        }
        a[0] += dpp_mov<0xB1>(a[4]);   // xor1
        a[1] += dpp_mov<0xB1>(a[5]);
        a[2] += dpp_mov<0xB1>(a[6]);
        a[3] += dpp_mov<0xB1>(a[7]);
        a[0] += dpp_mov<0x4E>(a[2]);   // xor2
        a[1] += dpp_mov<0x4E>(a[3]);
        a[0] += dpp_mov<0x140>(a[1]);  // xor15 (row_mirror)
        a[0] += dpp_mov<0x128>(a[0]);  // xor8  (row_ror:8)
        return a[0];
    };

    #pragma unroll 2
    for (int s = 0; s < TT + 2; ++s) {
        const int p = s & 1;
        const int q = p ^ 1;

        if (grp == 0) {
            // h0[s] = relu(Whh0.h0[s-1] + Wih0.x[s] + b)
            if (s < TT) {
                float acc = matvec(h0_lds[p]);
                float v = acc + bias;
                if (s < TIN) {
                    const float* xr = &x_lds[s * 8];
                    float4 xv = *(const float4*)xr;
                    float x4 = xr[4];
                    v = fmaf(wih0r[0], xv.x, v);
                    v = fmaf(wih0r[1], xv.y, v);
                    v = fmaf(wih0r[2], xv.z, v);
                    v = fmaf(wih0r[3], xv.w, v);
                    v = fmaf(wih0r[4], x4,   v);
                }
                if (writer) h0_lds[q][row] = fmaxf(v, 0.f);
            }
        } else if (grp == 1) {
            // A[s-1] = Wih1 . h0[s-1]
            if (s <= TT) {
                float acc = matvec(h0_lds[p]);
                if (writer) A_lds[q][row] = acc;
            }
            // batched y-dots: 8 sigmoids per visit, every 8th step
            if (s >= 10 && s <= 802 && ((s - 2) & 7) == 0) {
                const int u = (s - 10) + (lt >> 5);
                const int l = lt & 31;
                const float* hr = ring[u & 15];
                float v = hr[l      ] * wout_lds[l      ]
                        + hr[l + 32] * wout_lds[l + 32]
                        + hr[l + 64] * wout_lds[l + 64]
                        + hr[l + 96] * wout_lds[l + 96];
                v += __shfl_xor(v, 16, 64);
                v += __shfl_xor(v,  8, 64);
                v += __shfl_xor(v,  4, 64);
                v += __shfl_xor(v,  2, 64);
                v += __shfl_xor(v,  1, 64);
                if (l == 0) {
                    float z = v + bout;
                    out[bb * TIN + u] = 1.f / (1.f + expf(-z));
                }
            }
        } else {
            // h1[s-2] = relu(A[s-2] + Whh1.h1[s-3] + b)
            if (s >= 2) {
                const int u = s - 2;
                float acc = matvec(h1_lds[p]);
                float v = fmaxf(acc + bias + A_lds[p][row], 0.f);
                if (writer) {
                    h1_lds[q][row] = v;
                    if (u < TIN) ring[u & 15][row] = v;
                }
            }
        }
        __syncthreads();
    }

    // h0_lds[0] = h0[999] (written s=999,q=0); h1_lds[0] = h1[999] (s=1001,q=0)
    if (tid < HD) {
        out[TIN * BATCH + bb * HD + tid] = h0_lds[0][tid];
    } else if (tid < 2 * HD) {
        out[TIN * BATCH + BATCH * HD + bb * HD + (tid - HD)] = h1_lds[0][tid - HD];
    }
}

extern "C" void kernel_launch(void* const* d_in, const int* in_sizes, int n_in,
                              void* d_out, int out_size, void* d_ws, size_t ws_size,
                              hipStream_t stream) {
    (void)in_sizes; (void)n_in; (void)d_ws; (void)ws_size; (void)out_size;
    rnn_persist<<<dim3(BATCH), dim3(768), 0, stream>>>(
        (const float*)d_in[0],  (const float*)d_in[1],
        (const float*)d_in[2],  (const float*)d_in[3],
        (const float*)d_in[4],  (const float*)d_in[5],
        (const float*)d_in[6],  (const float*)d_in[7],
        (const float*)d_in[8],  (const float*)d_in[9],
        (const float*)d_in[10], (const float*)d_in[11],
        (float*)d_out);
}